// Round 2
// baseline (345.798 us; speedup 1.0000x reference)
//
#include <hip/hip_runtime.h>
#include <hip/hip_bf16.h>
#include <math.h>

// Problem constants
#define H   1024
#define Dd  200
#define Kc  8
#define Bb  8
#define Ll  4096
#define Mm  (Bb*Ll)  // 32768 rows
#define NT  13       // N tiles of 16 (208 cols, padded)

typedef __attribute__((ext_vector_type(8))) short short8;
typedef __attribute__((ext_vector_type(4))) float f32x4;

// ws layout (bytes)
#define OFF_W1T  0                           // bf16 [208][1024] = 425984 B
#define OFF_S    425984                      // f32 [Mm][8]     = 1048576 B
#define OFF_SEG  (OFF_S + Mm*Kc*4)           // f32 [8][16][8]  = 4096 B
#define OFF_PART (OFF_SEG + Bb*16*Kc*4)      // f32 [128]
#define WS_NEEDED (OFF_PART + 128*4)

__device__ __forceinline__ unsigned short f2bf(float x){
  unsigned u = __float_as_uint(x);
  unsigned r = (u + 0x7FFFu + ((u >> 16) & 1u)) >> 16;   // RNE
  return (unsigned short)r;
}

// ---------------- prep: W1 (fp32 [H][Dd]) -> W1T (bf16 [208][H], zero-padded cols)
__global__ __launch_bounds__(256) void prep_w1t(const float* __restrict__ W1,
                                                unsigned short* __restrict__ W1T){
  int idx = blockIdx.x * 256 + threadIdx.x;   // 0 .. 208*1024-1
  int d = idx >> 10;
  int h = idx & 1023;
  float v = (d < Dd) ? W1[h * Dd + d] : 0.f;
  W1T[idx] = f2bf(v);
}

// ---------------- fused GEMM1 (bf16 MFMA, LDS-free/barrier-free)
//                  + tanh + GEMM2 + mean-scale -> s
__global__ __launch_bounds__(256) void gemm_fused(const float* __restrict__ hidd,
                                                  const unsigned short* __restrict__ W1T,
                                                  const float* __restrict__ b1,
                                                  const float* __restrict__ W2,
                                                  const float* __restrict__ b2,
                                                  float* __restrict__ sOut){
  const int tid  = threadIdx.x;
  const int lane = tid & 63;
  const int wid  = tid >> 6;
  const int lc   = lane & 15;   // A-row / B-col within tile
  const int lg   = lane >> 4;   // k-slice group (8 k each)
  const long row0 = (long)blockIdx.x * 64 + wid * 16;

  const float*          ap = hidd + (row0 + lc) * H + lg * 8;
  const unsigned short* bp = W1T  + (long)lc * H + lg * 8;

  f32x4 acc[NT];
  #pragma unroll
  for (int t = 0; t < NT; ++t) acc[t] = (f32x4){0.f, 0.f, 0.f, 0.f};
  float ms = 0.f;

  // K loop: 32 steps of K=32. No LDS, no barriers — fragments straight from
  // global. A: 32B contiguous fp32 per lane (row-major hidd). B: 16B bf16
  // per lane from W1T[col][k] (L1/L2-resident, 416 KB shared by all waves).
  #pragma unroll 4
  for (int kt = 0; kt < 32; ++kt){
    const float4 a0 = *(const float4*)(ap + kt * 32);
    const float4 a1 = *(const float4*)(ap + kt * 32 + 4);
    ms += (a0.x + a0.y + a0.z + a0.w) + (a1.x + a1.y + a1.z + a1.w);
    short8 af;
    af[0] = (short)f2bf(a0.x); af[1] = (short)f2bf(a0.y);
    af[2] = (short)f2bf(a0.z); af[3] = (short)f2bf(a0.w);
    af[4] = (short)f2bf(a1.x); af[5] = (short)f2bf(a1.y);
    af[6] = (short)f2bf(a1.z); af[7] = (short)f2bf(a1.w);
    #pragma unroll
    for (int t = 0; t < NT; ++t){
      const short8 bf = *(const short8*)(bp + (long)t * 16 * H + kt * 32);
      acc[t] = __builtin_amdgcn_mfma_f32_16x16x32_bf16(af, bf, acc[t], 0, 0, 0);
    }
  }

  // full row sums: lane(lc,lg) holds partial over its k-slices; reduce over lg
  ms += __shfl_xor(ms, 16);
  ms += __shfl_xor(ms, 32);
  // means for the 4 C-rows this lane group owns (row = lg*4 + r, held by lane lg*4+r)
  float mr[4];
  #pragma unroll
  for (int r = 0; r < 4; ++r) mr[r] = __shfl(ms, lg * 4 + r) * (1.0f / 1024.0f);

  // epilogue: tanh + GEMM2 (in-register) + butterfly reduce over cols
  float part[4][Kc];
  #pragma unroll
  for (int r = 0; r < 4; ++r)
    #pragma unroll
    for (int k = 0; k < Kc; ++k) part[r][k] = 0.f;

  #pragma unroll
  for (int t = 0; t < NT; ++t){
    const int col = t * 16 + lc;
    float b1v = 0.f;
    float w2v[Kc];
    if (col < Dd){
      b1v = b1[col];
      const float4 wa = *(const float4*)(W2 + col * Kc);
      const float4 wb = *(const float4*)(W2 + col * Kc + 4);
      w2v[0] = wa.x; w2v[1] = wa.y; w2v[2] = wa.z; w2v[3] = wa.w;
      w2v[4] = wb.x; w2v[5] = wb.y; w2v[6] = wb.z; w2v[7] = wb.w;
    } else {
      #pragma unroll
      for (int k = 0; k < Kc; ++k) w2v[k] = 0.f;
    }
    #pragma unroll
    for (int r = 0; r < 4; ++r){
      const float a = tanhf(acc[t][r] + b1v);
      #pragma unroll
      for (int k = 0; k < Kc; ++k) part[r][k] = fmaf(a, w2v[k], part[r][k]);
    }
  }
  #pragma unroll
  for (int m = 1; m < 16; m <<= 1){
    #pragma unroll
    for (int r = 0; r < 4; ++r)
      #pragma unroll
      for (int k = 0; k < Kc; ++k)
        part[r][k] += __shfl_xor(part[r][k], m);
  }

  float b2r[Kc];
  #pragma unroll
  for (int k = 0; k < Kc; ++k) b2r[k] = b2[k];

  if (lc == 0){
    #pragma unroll
    for (int r = 0; r < 4; ++r){
      const long grow = row0 + lg * 4 + r;
      float4 o0, o1;
      o0.x = (part[r][0] + b2r[0]) * mr[r];
      o0.y = (part[r][1] + b2r[1]) * mr[r];
      o0.z = (part[r][2] + b2r[2]) * mr[r];
      o0.w = (part[r][3] + b2r[3]) * mr[r];
      o1.x = (part[r][4] + b2r[4]) * mr[r];
      o1.y = (part[r][5] + b2r[5]) * mr[r];
      o1.z = (part[r][6] + b2r[6]) * mr[r];
      o1.w = (part[r][7] + b2r[7]) * mr[r];
      *(float4*)(sOut + grow * Kc)     = o0;
      *(float4*)(sOut + grow * Kc + 4) = o1;
    }
  }
}

// ---------------- per-(batch,segment) channel sums
__global__ __launch_bounds__(256) void seg_sum(const float* __restrict__ s,
                                               float* __restrict__ segs){
  int b   = blockIdx.x >> 4;
  int seg = blockIdx.x & 15;
  int tid = threadIdx.x, lane = tid & 63, wid = tid >> 6;
  int l = seg * 256 + tid;
  const float4* sp = (const float4*)(s + ((long)(b * Ll + l)) * Kc);
  float4 v0 = sp[0], v1 = sp[1];
  float v[8] = {v0.x, v0.y, v0.z, v0.w, v1.x, v1.y, v1.z, v1.w};
  #pragma unroll
  for (int k = 0; k < 8; ++k){
    float x = v[k];
    x += __shfl_xor(x, 1);  x += __shfl_xor(x, 2);  x += __shfl_xor(x, 4);
    x += __shfl_xor(x, 8);  x += __shfl_xor(x, 16); x += __shfl_xor(x, 32);
    v[k] = x;
  }
  __shared__ float part[4][8];
  if (lane == 0){
    #pragma unroll
    for (int k = 0; k < 8; ++k) part[wid][k] = v[k];
  }
  __syncthreads();
  if (tid < 8){
    float t = part[0][tid] + part[1][tid] + part[2][tid] + part[3][tid];
    segs[(b * 16 + seg) * 8 + tid] = t;
  }
}

// ---------------- scan + det + softmax + log_softmax + pick -> partial loss
__global__ __launch_bounds__(256) void scan_loss(const float* __restrict__ s,
                                                 const float* __restrict__ segs,
                                                 const int* __restrict__ ptypes,
                                                 const int* __restrict__ labels,
                                                 float* __restrict__ partial){
  int b   = blockIdx.x >> 4;
  int seg = blockIdx.x & 15;
  int tid = threadIdx.x, lane = tid & 63, wid = tid >> 6;
  int l = seg * 256 + tid;

  float carry[8], T[8];
  #pragma unroll
  for (int k = 0; k < 8; ++k){ carry[k] = 0.f; T[k] = 0.f; }
  for (int ss = 0; ss < 16; ++ss){
    #pragma unroll
    for (int k = 0; k < 8; ++k){
      float x = segs[(b * 16 + ss) * 8 + k];
      T[k] += x;
      if (ss < seg) carry[k] += x;
    }
  }

  const float4* sp = (const float4*)(s + ((long)(b * Ll + l)) * Kc);
  float4 v0 = sp[0], v1 = sp[1];
  float sv[8] = {v0.x, v0.y, v0.z, v0.w, v1.x, v1.y, v1.z, v1.w};
  float P[8];
  #pragma unroll
  for (int k = 0; k < 8; ++k) P[k] = sv[k];

  // inclusive scan within wave, per channel
  #pragma unroll
  for (int st = 1; st < 64; st <<= 1){
    #pragma unroll
    for (int k = 0; k < 8; ++k){
      float u = __shfl_up(P[k], st);
      if (lane >= st) P[k] += u;
    }
  }
  __shared__ float wsum[4][8];
  if (lane == 63){
    #pragma unroll
    for (int k = 0; k < 8; ++k) wsum[wid][k] = P[k];
  }
  __syncthreads();
  for (int w = 0; w < wid; ++w){
    #pragma unroll
    for (int k = 0; k < 8; ++k) P[k] += wsum[w][k];
  }
  #pragma unroll
  for (int k = 0; k < 8; ++k) P[k] += carry[k];

  int pt = ptypes[b];
  float det[8];
  if (pt == 0){
    float inv = 1.0f / (float)(l + 1);
    #pragma unroll
    for (int k = 0; k < 8; ++k) det[k] = P[k] * inv;
  } else if (pt == 1){
    float inv = 1.0f / (float)(Ll - l);
    #pragma unroll
    for (int k = 0; k < 8; ++k) det[k] = (T[k] - P[k] + sv[k]) * inv;
  } else {
    #pragma unroll
    for (int k = 0; k < 8; ++k) det[k] = sv[k];
  }

  // softmax
  float mx = det[0];
  #pragma unroll
  for (int k = 1; k < 8; ++k) mx = fmaxf(mx, det[k]);
  float e[8], Z = 0.f;
  #pragma unroll
  for (int k = 0; k < 8; ++k){ e[k] = expf(det[k] - mx); Z += e[k]; }
  float invZ = 1.0f / Z;
  float p[8];
  #pragma unroll
  for (int k = 0; k < 8; ++k) p[k] = e[k] * invZ;
  // log_softmax of p
  float mx2 = p[0];
  #pragma unroll
  for (int k = 1; k < 8; ++k) mx2 = fmaxf(mx2, p[k]);
  float Z2 = 0.f;
  #pragma unroll
  for (int k = 0; k < 8; ++k) Z2 += expf(p[k] - mx2);
  float lse = logf(Z2) + mx2;

  int lab = labels[b * Ll + l];
  float picked = 0.f;
  #pragma unroll
  for (int k = 0; k < 8; ++k) picked = (lab == k) ? (p[k] - lse) : picked;

  // block reduce
  float a = picked;
  a += __shfl_xor(a, 1);  a += __shfl_xor(a, 2);  a += __shfl_xor(a, 4);
  a += __shfl_xor(a, 8);  a += __shfl_xor(a, 16); a += __shfl_xor(a, 32);
  __shared__ float red[4];
  if (lane == 0) red[wid] = a;
  __syncthreads();
  if (tid == 0){
    partial[blockIdx.x] = red[0] + red[1] + red[2] + red[3];
  }
}

// ---------------- final: out[b] = -sum(partial[b*16 .. +15]) / L
__global__ __launch_bounds__(128) void final_loss(const float* __restrict__ partial,
                                                  float* __restrict__ out){
  int tid = threadIdx.x;  // 0..127 -> b = tid>>4
  float v = partial[tid];
  v += __shfl_xor(v, 1); v += __shfl_xor(v, 2);
  v += __shfl_xor(v, 4); v += __shfl_xor(v, 8);
  if ((tid & 15) == 0) out[tid >> 4] = -v * (1.0f / (float)Ll);
}

extern "C" void kernel_launch(void* const* d_in, const int* in_sizes, int n_in,
                              void* d_out, int out_size, void* d_ws, size_t ws_size,
                              hipStream_t stream){
  const float* hidd  = (const float*)d_in[0];
  const float* W1    = (const float*)d_in[1];
  const float* b1    = (const float*)d_in[2];
  const float* W2    = (const float*)d_in[3];
  const float* b2    = (const float*)d_in[4];
  const int* ptypes  = (const int*)d_in[5];
  const int* labels  = (const int*)d_in[6];
  float* out = (float*)d_out;
  char* ws = (char*)d_ws;
  if (ws_size < (size_t)WS_NEEDED) return;

  unsigned short* W1T = (unsigned short*)(ws + OFF_W1T);
  float* s       = (float*)(ws + OFF_S);
  float* segs    = (float*)(ws + OFF_SEG);
  float* partial = (float*)(ws + OFF_PART);

  prep_w1t<<<(208 * H) / 256, 256, 0, stream>>>(W1, W1T);
  gemm_fused<<<Mm / 64, 256, 0, stream>>>(hidd, W1T, b1, W2, b2, s);
  seg_sum<<<Bb * 16, 256, 0, stream>>>(s, segs);
  scan_loss<<<Bb * 16, 256, 0, stream>>>(s, segs, ptypes, labels, partial);
  final_loss<<<1, 128, 0, stream>>>(partial, out);
}